// Round 6
// baseline (4785.928 us; speedup 1.0000x reference)
//
#include <hip/hip_runtime.h>
#include <hip/hip_bf16.h>

#define SEQ_   128
#define NCLS_  50257
#define EMB_   1024
#define HID_   1024
#define BATCH_ 1024
#define G4_    4096

typedef __attribute__((ext_vector_type(8))) short short8;
typedef __attribute__((ext_vector_type(4))) float f32x4;

__device__ __forceinline__ void async_copy16(void* lds, const void* g) {
  __builtin_amdgcn_global_load_lds(
      (const __attribute__((address_space(1))) void*)g,
      (__attribute__((address_space(3))) void*)lds, 16, 0, 0);
}

__device__ __forceinline__ void mfma_acc(f32x4& c, const short8& a, const short8& b) {
  asm("v_mfma_f32_16x16x32_bf16 %0, %1, %2, %0" : "+v"(c) : "v"(a), "v"(b));
}

__device__ __forceinline__ float sigmoidf_(float x) {
  return 1.f / (1.f + __expf(-x));
}
__device__ __forceinline__ float tanhf_(float x) {
  x = fminf(12.f, fmaxf(-12.f, x));
  float e = __expf(2.f * x);
  return (e - 1.f) / (e + 1.f);
}
__device__ __forceinline__ float bf2f_(ushort u) {
  return __uint_as_float(((unsigned int)u) << 16);
}

// ---------------------------------------------------------------------------
// MFMA GEMM: C[M,N] = A[M,K] x Bt[N,K] (both bf16, rows k-XOR-swizzled:
// within each 64-elem k-group, 8-elem chunk index ^= row&7). BK=64,
// double-buffered LDS (A0|A1|B0|B1 x 16 KB), counted vmcnt(8).
// EPI 0: outB = bf16(acc + bias0[col])   (E_proj; bias pre-permuted)
// EPI 2: outF = acc + bias0[col]         (logits)
// ---------------------------------------------------------------------------
template <int EPI>
__global__ __launch_bounds__(256) void gemm_bt(
    const __hip_bfloat16* __restrict__ A, const __hip_bfloat16* __restrict__ Bt,
    float* __restrict__ outF, __hip_bfloat16* __restrict__ outB,
    int Mreal, int Nreal, int K, long ostride,
    const float* __restrict__ bias0) {
  __shared__ __align__(16) char smem[65536];

  const int tid = threadIdx.x;
  const int lane = tid & 63;
  const int w = tid >> 6;
  const int wm = w >> 1;
  const int wn = w & 1;
  const int m0 = blockIdx.y * 128;
  const int n0 = blockIdx.x * 128;

  const int fr = lane & 15;
  const int kb = (lane >> 4) * 16;
  const int swz = (fr & 7) << 4;

  f32x4 acc[4][4];
#pragma unroll
  for (int i = 0; i < 4; ++i)
#pragma unroll
    for (int j = 0; j < 4; ++j) acc[i][j] = (f32x4)(0.0f);

  auto STAGE = [&](int kc, int b) {
#pragma unroll
    for (int q = 0; q < 8; ++q) {
      const int ridx = (q & 3) * 256 + tid;   // 0..1023
      const int row = ridx >> 3;              // 0..127
      const int ch = ridx & 7;
      const __hip_bfloat16* src;
      char* dst;
      if (q < 4) {
        long ar = m0 + row; if (ar >= Mreal) ar = Mreal - 1;
        src = A + ar * (long)K + kc * 64 + ch * 8;
        dst = smem + b * 16384 + ridx * 16;
      } else {
        long br = n0 + row; if (br >= Nreal) br = Nreal - 1;
        src = Bt + br * (long)K + kc * 64 + ch * 8;
        dst = smem + 32768 + b * 16384 + ridx * 16;
      }
      async_copy16(dst, src);
    }
  };

  const int KC = K >> 6;
  STAGE(0, 0);
  for (int kc = 0; kc < KC; ++kc) {
    const int b = kc & 1;
    if (kc + 1 < KC) {
      STAGE(kc + 1, b ^ 1);
      asm volatile("s_waitcnt vmcnt(8)" ::: "memory");
    } else {
      asm volatile("s_waitcnt vmcnt(0)" ::: "memory");
    }
    __builtin_amdgcn_s_barrier();
    __builtin_amdgcn_sched_barrier(0);

    short8 aR[2][4], bR[2][4];
#pragma unroll
    for (int kk = 0; kk < 2; ++kk)
#pragma unroll
      for (int f = 0; f < 4; ++f) {
        aR[kk][f] = *(const short8*)(smem + b * 16384 +
                     (wm * 64 + f * 16 + fr) * 128 + ((kk * 64 + kb) ^ swz));
        bR[kk][f] = *(const short8*)(smem + 32768 + b * 16384 +
                     (wn * 64 + f * 16 + fr) * 128 + ((kk * 64 + kb) ^ swz));
      }
#pragma unroll
    for (int fm = 0; fm < 4; ++fm)
#pragma unroll
      for (int fn = 0; fn < 4; ++fn) {
        mfma_acc(acc[fm][fn], aR[0][fm], bR[0][fn]);
        mfma_acc(acc[fm][fn], aR[1][fm], bR[1][fn]);
      }
    __builtin_amdgcn_sched_barrier(0);
    __builtin_amdgcn_s_barrier();
  }

  const int cn = lane & 15;
  const int rb = (lane >> 4) * 4;
#pragma unroll
  for (int fn = 0; fn < 4; ++fn) {
    const int col = n0 + wn * 64 + fn * 16 + cn;
    const float badd = (col < Nreal) ? bias0[col] : 0.f;
#pragma unroll
    for (int fm = 0; fm < 4; ++fm) {
#pragma unroll
      for (int r = 0; r < 4; ++r) {
        const int row = m0 + wm * 64 + fm * 16 + rb + r;
        const float v = acc[fm][fn][r] + badd;
        if (EPI == 0) {
          if (row < Mreal) outB[(long)row * ostride + col] = __float2bfloat16(v);
        } else {
          if (col < Nreal && row < Mreal) outF[(long)row * ostride + col] = v;
        }
      }
    }
  }
}

// ---------------------------------------------------------------------------
// ALL 128 LSTM steps in ONE cooperative kernel. Grid 256 x 512 threads.
// stripe = bid>>5 (128 batch rows); slice = bid&31 (32 h x 4 gates).
// The time recurrence only couples blocks within a stripe (same batch rows),
// so each step ends with a 32-block stripe barrier (atomic + agent fences),
// NOT a device-wide grid.sync. c state lives in registers for all 128 steps.
// Waves: (wm,wn) 2x2 output tiles x kh 2 K-halves; partials merged in LDS.
// hbuf ping-pong [2][1024][1024] bf16 k-swizzled; final h lands in hbuf[0].
// ---------------------------------------------------------------------------
__global__ __launch_bounds__(512) void lstm_all(
    const __hip_bfloat16* __restrict__ Whs,     // [4096][1024] swizzled
    const __hip_bfloat16* __restrict__ Epr,     // [V][4096] col=4h+g, plain
    const int* __restrict__ X,
    __hip_bfloat16* __restrict__ hbuf,          // [2][1024][1024] swizzled
    int* __restrict__ bar) {                    // [8] zeroed each call
  extern __shared__ __align__(16) char smem[];  // 128 KB staging / gacc union
  float* gacc = (float*)smem;                   // [128][132] f32

  const int tid = threadIdx.x;
  const int lane = tid & 63;
  const int w = tid >> 6;        // 0..7
  const int wm = (w >> 1) & 1;
  const int wn = w & 1;
  const int kh = w >> 2;         // K-half
  const int bid = blockIdx.x;
  const int stripe = bid >> 5;   // batch-row stripe (independent recurrence)
  const int slice = bid & 31;    // h/gate slice; XCD = bid%8 = slice%8
  const int m0 = stripe * 128;
  const int h0 = slice * 32;

  const int fr = lane & 15;
  const int kb = (lane >> 4) * 16;
  const int swz = (fr & 7) << 4;
  const int cn = lane & 15;
  const int rb = (lane >> 4) * 4;

  const int crow = tid >> 2;     // cell row 0..127
  const int hq = tid & 3;        // h quarter (8 h each)
  const int prow = m0 + crow;

  float cst[8];
#pragma unroll
  for (int jj = 0; jj < 8; ++jj) cst[jj] = 0.f;

#pragma unroll 1
  for (int t = 0; t < SEQ_; ++t) {
    const __hip_bfloat16* hcur = hbuf + (size_t)(t & 1) * (1024 * 1024);
    __hip_bfloat16* hnxt = hbuf + (size_t)((t + 1) & 1) * (1024 * 1024);

    // token load issued first; Eps gather issued after STAGE(0) so the
    // dependent-load stall overlaps the staging flight.
    const int tok1 = X[prow * SEQ_ + t];

    f32x4 acc[4][4];  // [fm][gate]
#pragma unroll
    for (int i = 0; i < 4; ++i)
#pragma unroll
      for (int g = 0; g < 4; ++g) acc[i][g] = (f32x4)(0.0f);

    auto STAGE = [&](int kc, int b) {
#pragma unroll
      for (int q = 0; q < 8; ++q) {
        const int region = q >> 1;           // A_h0,A_h1,B_h0,B_h1
        const int r = (q & 1) * 512 + tid;   // 0..1023
        const int row = r >> 3;              // 0..127
        const int ch = r & 7;
        const __hip_bfloat16* src;
        if (region < 2) {
          src = hcur + (size_t)(m0 + row) * HID_ + region * 512 + kc * 64 + ch * 8;
        } else {
          const int g = row >> 5, hh = row & 31;
          src = Whs + (size_t)(g * 1024 + h0 + hh) * HID_ + (region - 2) * 512 +
                kc * 64 + ch * 8;
        }
        async_copy16(smem + region * 32768 + b * 16384 + r * 16, src);
      }
    };

    STAGE(0, 0);

    ushort4 ep[8];
#pragma unroll
    for (int jj = 0; jj < 8; ++jj)
      ep[jj] = *(const ushort4*)(Epr + (size_t)tok1 * G4_ + (h0 + hq * 8 + jj) * 4);

    for (int kc = 0; kc < 8; ++kc) {
      const int b = kc & 1;
      if (kc < 7) {
        STAGE(kc + 1, b ^ 1);
        asm volatile("s_waitcnt vmcnt(8)" ::: "memory");
      } else {
        asm volatile("s_waitcnt vmcnt(0)" ::: "memory");
      }
      __builtin_amdgcn_s_barrier();
      __builtin_amdgcn_sched_barrier(0);

      const char* baseA = smem + kh * 32768 + b * 16384;
      const char* baseB = smem + 65536 + kh * 32768 + b * 16384;
      short8 aR[2][4], bR[2][4];
#pragma unroll
      for (int kk = 0; kk < 2; ++kk)
#pragma unroll
        for (int f = 0; f < 4; ++f) {
          aR[kk][f] = *(const short8*)(baseA + (wm * 64 + f * 16 + fr) * 128 +
                                       ((kk * 64 + kb) ^ swz));
          bR[kk][f] = *(const short8*)(baseB + (f * 32 + wn * 16 + fr) * 128 +
                                       ((kk * 64 + kb) ^ swz));
        }
#pragma unroll
      for (int fm = 0; fm < 4; ++fm)
#pragma unroll
        for (int g = 0; g < 4; ++g) {
          mfma_acc(acc[fm][g], aR[0][fm], bR[0][g]);
          mfma_acc(acc[fm][g], aR[1][fm], bR[1][g]);
        }
      __builtin_amdgcn_sched_barrier(0);
      __builtin_amdgcn_s_barrier();
    }

    // ---- merge K-half partials in LDS (gacc col = 4*h_local + gate)
    if (kh == 0) {
#pragma unroll
      for (int fm = 0; fm < 4; ++fm)
#pragma unroll
        for (int g = 0; g < 4; ++g)
#pragma unroll
          for (int r = 0; r < 4; ++r)
            gacc[(wm * 64 + fm * 16 + rb + r) * 132 + (wn * 16 + cn) * 4 + g] =
                acc[fm][g][r];
    }
    __syncthreads();
    if (kh == 1) {
#pragma unroll
      for (int fm = 0; fm < 4; ++fm)
#pragma unroll
        for (int g = 0; g < 4; ++g)
#pragma unroll
          for (int r = 0; r < 4; ++r)
            gacc[(wm * 64 + fm * 16 + rb + r) * 132 + (wn * 16 + cn) * 4 + g] +=
                acc[fm][g][r];
    }
    __syncthreads();

    // ---- fused cell: thread = (crow, hq), 8 h each, all 4 gates local
    const float* gr = gacc + crow * 132 + hq * 32;
    short8 hv;
#pragma unroll
    for (int jj = 0; jj < 8; ++jj) {
      const f32x4 g4 = *(const f32x4*)(gr + jj * 4);
      const float iv = sigmoidf_(g4[0] + bf2f_(ep[jj].x));
      const float fv = sigmoidf_(g4[1] + bf2f_(ep[jj].y));
      const float gv = tanhf_(g4[2] + bf2f_(ep[jj].z));
      const float ov = sigmoidf_(g4[3] + bf2f_(ep[jj].w));
      const float cv = fv * cst[jj] + iv * gv;
      cst[jj] = cv;
      const float hval = ov * tanhf_(cv);
      const __hip_bfloat16 hb = __float2bfloat16(hval);
      hv[jj] = *reinterpret_cast<const short*>(&hb);
    }
    const int hcolb = h0 + hq * 8;
    const int hswb = (hcolb & ~63) | ((hcolb & 63) ^ ((prow & 7) << 3));
    *(short8*)(hnxt + (size_t)prow * HID_ + hswb) = hv;

    // ---- stripe barrier: 32 blocks sharing these batch rows.
    // __syncthreads drains vmcnt (stores at L2); release fence publishes,
    // acquire fence invalidates stale L1/L2 before next step's reads.
    __syncthreads();
    if (tid == 0) {
      __builtin_amdgcn_fence(__ATOMIC_RELEASE, "agent");
      atomicAdd(&bar[stripe], 1);
      const int target = 32 * (t + 1);
      while (__hip_atomic_load(&bar[stripe], __ATOMIC_RELAXED,
                               __HIP_MEMORY_SCOPE_AGENT) < target)
        __builtin_amdgcn_s_sleep(2);
      __builtin_amdgcn_fence(__ATOMIC_ACQUIRE, "agent");
    }
    __syncthreads();
  }
}

// fp32 -> bf16 flat convert; SWZ: k-XOR-swizzle per 64-col group (1024 cols)
template <bool SWZ>
__global__ __launch_bounds__(256) void conv_bf16_k(const float* __restrict__ in,
                                                   __hip_bfloat16* __restrict__ out, int n4) {
  const int i = blockIdx.x * 256 + threadIdx.x;
  if (i >= n4) return;
  const float4 v = ((const float4*)in)[i];
  int o = i * 4;
  if (SWZ) {
    const int row = o >> 10, col = o & 1023;
    const int cs = (col & ~63) | ((col & 63) ^ ((row & 7) << 3));
    o = (o & ~1023) | cs;
  }
  out[o + 0] = __float2bfloat16(v.x);
  out[o + 1] = __float2bfloat16(v.y);
  out[o + 2] = __float2bfloat16(v.z);
  out[o + 3] = __float2bfloat16(v.w);
}

// in[R][C] fp32 -> out[C][R] bf16; PERM: gate-interleave out-rows (4h+g);
// SWZ: XOR-swizzle k (cols of out) per 64-group by out-row&7.
template <bool PERM, bool SWZ>
__global__ __launch_bounds__(256) void transpose_conv(const float* __restrict__ in,
                                                      __hip_bfloat16* __restrict__ out,
                                                      int R, int C) {
  __shared__ float tile[32][33];
  const int c0 = blockIdx.x * 32, r0 = blockIdx.y * 32;
  const int tx = threadIdx.x, ty = threadIdx.y;  // 32x8
#pragma unroll
  for (int i = 0; i < 4; ++i) {
    const int r = r0 + ty + i * 8, cc = c0 + tx;
    tile[ty + i * 8][tx] = (r < R && cc < C) ? in[(size_t)r * C + cc] : 0.f;
  }
  __syncthreads();
#pragma unroll
  for (int i = 0; i < 4; ++i) {
    const int ro = c0 + ty + i * 8, co = r0 + tx;
    if (ro < C && co < R) {
      const int n = PERM ? ((ro & 1023) * 4 + (ro >> 10)) : ro;
      int k = co;
      if (SWZ) k = (k & ~63) | ((k & 63) ^ ((n & 7) << 3));
      out[(size_t)n * R + k] = __float2bfloat16(tile[tx][ty + i * 8]);
    }
  }
}

// bP[4h+g] = bx[g*1024+h] + bh[g*1024+h]
__global__ __launch_bounds__(256) void bias_perm(const float* __restrict__ bx,
                                                 const float* __restrict__ bh,
                                                 float* __restrict__ bP) {
  const int n = blockIdx.x * 256 + threadIdx.x;
  if (n >= G4_) return;
  const int h = n >> 2, g = n & 3;
  bP[n] = bx[g * HID_ + h] + bh[g * HID_ + h];
}

extern "C" void kernel_launch(void* const* d_in, const int* in_sizes, int n_in,
                              void* d_out, int out_size, void* d_ws, size_t ws_size,
                              hipStream_t stream) {
  const int* X = (const int*)d_in[0];
  const float* C = (const float*)d_in[1];
  const float* Wx = (const float*)d_in[2];
  const float* bx = (const float*)d_in[3];
  const float* Wh = (const float*)d_in[4];
  const float* bh = (const float*)d_in[5];
  const float* Wo = (const float*)d_in[6];
  const float* bo = (const float*)d_in[7];
  float* out = (float*)d_out;

  char* p = (char*)d_ws;
  const size_t szCb  = (size_t)NCLS_ * EMB_ * 2;   // Cb, reused for Wot
  const size_t szWxt = (size_t)G4_ * EMB_ * 2;
  const size_t szWhs = (size_t)G4_ * HID_ * 2;
  const size_t szEpr = (size_t)NCLS_ * G4_ * 2;
  const size_t szHb  = (size_t)2 * BATCH_ * HID_ * 2;  // ping-pong
  const size_t szBp  = (size_t)G4_ * 4;
  const size_t szBar = 128;
  if (ws_size < szCb + szWxt + szWhs + szEpr + szHb + szBp + szBar) return;

  __hip_bfloat16* Cb   = (__hip_bfloat16*)p; p += szCb;
  __hip_bfloat16* WxtP = (__hip_bfloat16*)p; p += szWxt;
  __hip_bfloat16* Whs  = (__hip_bfloat16*)p; p += szWhs;
  __hip_bfloat16* Epr  = (__hip_bfloat16*)p; p += szEpr;
  __hip_bfloat16* hbuf = (__hip_bfloat16*)p; p += szHb;
  float* bP            = (float*)p;          p += szBp;
  int* bar             = (int*)p;            p += szBar;

  // 1. C -> bf16, k-swizzled (A operand of E_proj GEMM)
  {
    const int n4 = NCLS_ * EMB_ / 4;
    conv_bf16_k<true><<<(n4 + 255) / 256, 256, 0, stream>>>(C, Cb, n4);
  }
  // 2. Wx -> [4096][1024] gate-interleaved rows, k-swizzled
  transpose_conv<true, true><<<dim3(G4_ / 32, EMB_ / 32), dim3(32, 8), 0, stream>>>(
      Wx, WxtP, EMB_, G4_);
  // 3. Wh -> [4096][1024] plain rows (n = g*1024+h), k-swizzled
  transpose_conv<false, true><<<dim3(G4_ / 32, HID_ / 32), dim3(32, 8), 0, stream>>>(
      Wh, Whs, HID_, G4_);
  // 4. permuted bias
  bias_perm<<<G4_ / 256, 256, 0, stream>>>(bx, bh, bP);

  // 5. Epr[V][4096] = C @ Wx (gate-interleaved cols) + (bx+bh), plain layout
  gemm_bt<0><<<dim3(G4_ / 128, (NCLS_ + 127) / 128), 256, 0, stream>>>(
      Cb, WxtP, nullptr, Epr, NCLS_, G4_, EMB_, G4_, bP);

  // 6. zero h[0] (t=0 input; also the final-h buffer) + barrier counters
  hipMemsetAsync(hbuf, 0, (size_t)BATCH_ * HID_ * 2, stream);
  hipMemsetAsync(bar, 0, szBar, stream);

  // 7. ALL 128 LSTM steps, one cooperative launch (stripe-local barriers)
  {
    void* kargs[] = {(void*)&Whs, (void*)&Epr, (void*)&X, (void*)&hbuf, (void*)&bar};
    hipLaunchCooperativeKernel((void*)lstm_all, dim3(256), dim3(512), kargs,
                               131072, stream);
  }

  // 8. W_out^T, k-swizzled, into Cb region (dead after step 5)
  __hip_bfloat16* Wot = Cb;
  transpose_conv<false, true><<<dim3((NCLS_ + 31) / 32, HID_ / 32), dim3(32, 8), 0,
                                stream>>>(Wo, Wot, HID_, NCLS_);

  // 9. logits = h_final @ W_out + b_out  (h_final = hbuf[0], swizzled)
  gemm_bt<2><<<dim3((NCLS_ + 127) / 128, BATCH_ / 128), 256, 0, stream>>>(
      hbuf, Wot, out, nullptr, BATCH_, NCLS_, HID_, NCLS_, bo);
}

// Round 7
// 3161.759 us; speedup vs baseline: 1.5137x; 1.5137x over previous
//
#include <hip/hip_runtime.h>
#include <hip/hip_bf16.h>

#define SEQ_   128
#define NCLS_  50257
#define EMB_   1024
#define HID_   1024
#define BATCH_ 1024
#define G4_    4096

typedef __attribute__((ext_vector_type(8))) short short8;
typedef __attribute__((ext_vector_type(4))) float f32x4;

__device__ __forceinline__ void async_copy16(void* lds, const void* g) {
  __builtin_amdgcn_global_load_lds(
      (const __attribute__((address_space(1))) void*)g,
      (__attribute__((address_space(3))) void*)lds, 16, 0, 0);
}

__device__ __forceinline__ void mfma_acc(f32x4& c, const short8& a, const short8& b) {
  asm("v_mfma_f32_16x16x32_bf16 %0, %1, %2, %0" : "+v"(c) : "v"(a), "v"(b));
}

__device__ __forceinline__ float sigmoidf_(float x) {
  return 1.f / (1.f + __expf(-x));
}
__device__ __forceinline__ float tanhf_(float x) {
  x = fminf(12.f, fmaxf(-12.f, x));
  float e = __expf(2.f * x);
  return (e - 1.f) / (e + 1.f);
}
__device__ __forceinline__ float bf2f_(ushort u) {
  return __uint_as_float(((unsigned int)u) << 16);
}

// ---------------------------------------------------------------------------
// MFMA GEMM (unchanged from r5): C = A[M,K] x Bt[N,K], k-XOR-swizzled rows,
// BK=64 double-buffered, counted vmcnt(8).
// EPI 0: outB = bf16(acc + bias0[col]) ; EPI 2: outF = acc + bias0[col]
// ---------------------------------------------------------------------------
template <int EPI>
__global__ __launch_bounds__(256) void gemm_bt(
    const __hip_bfloat16* __restrict__ A, const __hip_bfloat16* __restrict__ Bt,
    float* __restrict__ outF, __hip_bfloat16* __restrict__ outB,
    int Mreal, int Nreal, int K, long ostride,
    const float* __restrict__ bias0) {
  __shared__ __align__(16) char smem[65536];

  const int tid = threadIdx.x;
  const int lane = tid & 63;
  const int w = tid >> 6;
  const int wm = w >> 1;
  const int wn = w & 1;
  const int m0 = blockIdx.y * 128;
  const int n0 = blockIdx.x * 128;

  const int fr = lane & 15;
  const int kb = (lane >> 4) * 16;
  const int swz = (fr & 7) << 4;

  f32x4 acc[4][4];
#pragma unroll
  for (int i = 0; i < 4; ++i)
#pragma unroll
    for (int j = 0; j < 4; ++j) acc[i][j] = (f32x4)(0.0f);

  auto STAGE = [&](int kc, int b) {
#pragma unroll
    for (int q = 0; q < 8; ++q) {
      const int ridx = (q & 3) * 256 + tid;
      const int row = ridx >> 3;
      const int ch = ridx & 7;
      const __hip_bfloat16* src;
      char* dst;
      if (q < 4) {
        long ar = m0 + row; if (ar >= Mreal) ar = Mreal - 1;
        src = A + ar * (long)K + kc * 64 + ch * 8;
        dst = smem + b * 16384 + ridx * 16;
      } else {
        long br = n0 + row; if (br >= Nreal) br = Nreal - 1;
        src = Bt + br * (long)K + kc * 64 + ch * 8;
        dst = smem + 32768 + b * 16384 + ridx * 16;
      }
      async_copy16(dst, src);
    }
  };

  const int KC = K >> 6;
  STAGE(0, 0);
  for (int kc = 0; kc < KC; ++kc) {
    const int b = kc & 1;
    if (kc + 1 < KC) {
      STAGE(kc + 1, b ^ 1);
      asm volatile("s_waitcnt vmcnt(8)" ::: "memory");
    } else {
      asm volatile("s_waitcnt vmcnt(0)" ::: "memory");
    }
    __builtin_amdgcn_s_barrier();
    __builtin_amdgcn_sched_barrier(0);

    short8 aR[2][4], bR[2][4];
#pragma unroll
    for (int kk = 0; kk < 2; ++kk)
#pragma unroll
      for (int f = 0; f < 4; ++f) {
        aR[kk][f] = *(const short8*)(smem + b * 16384 +
                     (wm * 64 + f * 16 + fr) * 128 + ((kk * 64 + kb) ^ swz));
        bR[kk][f] = *(const short8*)(smem + 32768 + b * 16384 +
                     (wn * 64 + f * 16 + fr) * 128 + ((kk * 64 + kb) ^ swz));
      }
#pragma unroll
    for (int fm = 0; fm < 4; ++fm)
#pragma unroll
      for (int fn = 0; fn < 4; ++fn) {
        mfma_acc(acc[fm][fn], aR[0][fm], bR[0][fn]);
        mfma_acc(acc[fm][fn], aR[1][fm], bR[1][fn]);
      }
    __builtin_amdgcn_sched_barrier(0);
    __builtin_amdgcn_s_barrier();
  }

  const int cn = lane & 15;
  const int rb = (lane >> 4) * 4;
#pragma unroll
  for (int fn = 0; fn < 4; ++fn) {
    const int col = n0 + wn * 64 + fn * 16 + cn;
    const float badd = (col < Nreal) ? bias0[col] : 0.f;
#pragma unroll
    for (int fm = 0; fm < 4; ++fm) {
#pragma unroll
      for (int r = 0; r < 4; ++r) {
        const int row = m0 + wm * 64 + fm * 16 + rb + r;
        const float v = acc[fm][fn][r] + badd;
        if (EPI == 0) {
          if (row < Mreal) outB[(long)row * ostride + col] = __float2bfloat16(v);
        } else {
          if (col < Nreal && row < Mreal) outF[(long)row * ostride + col] = v;
        }
      }
    }
  }
}

// ---------------------------------------------------------------------------
// Pack Wh into MFMA-fragment order: tile = ((ht*2+wn)*2+kh)*64 + kc*8 + kk*4
// + g, each tile 1 KB (lane-major: lane l holds col h=(l&15), k-slot l>>4).
// A wave's bR load is then one fully coalesced global_load_dwordx4.
// ---------------------------------------------------------------------------
__global__ __launch_bounds__(256) void pack_b(const float* __restrict__ Wh,
                                              __hip_bfloat16* __restrict__ Bpk) {
  const int gtid = blockIdx.x * 256 + threadIdx.x;  // 0..524287
  const int l = gtid & 63;
  const int tile = gtid >> 6;                       // 0..8191
  const int g = tile & 3;
  const int kk = (tile >> 2) & 1;
  const int kc = (tile >> 3) & 7;
  const int kh = (tile >> 6) & 1;
  const int wn = (tile >> 7) & 1;
  const int ht = tile >> 8;
  const int h = ht * 32 + wn * 16 + (l & 15);
  const int k0 = kh * 512 + kc * 64 + kk * 32 + (l >> 4) * 8;
  short8 v;
#pragma unroll
  for (int e = 0; e < 8; ++e) {
    const __hip_bfloat16 b = __float2bfloat16(Wh[(size_t)(k0 + e) * G4_ + g * 1024 + h]);
    v[e] = *reinterpret_cast<const short*>(&b);
  }
  *(short8*)(Bpk + (size_t)gtid * 8) = v;
}

// ---------------------------------------------------------------------------
// Fused LSTM step v3. Grid 256 (8 mt x 32 ht), 512 threads (8 waves).
// Waves: (wm,wn) 2x2 x kh 2 K-halves. fn indexes the GATE (cell fuses).
// A (hprev, k-swizzled) staged via global_load_lds, TRIPLE-buffered BK=64,
// ONE barrier per kc, counted vmcnt (A at distance 2; never 0 mid-loop).
// B (Whr) loaded straight to registers from fragment-packed Bpk (L2-resident
// per XCD), software-pipelined 1 deep; compiler manages its waits.
// K-half partials merged in LDS (gacc aliases dead A bufs); cell fused.
// ---------------------------------------------------------------------------
__global__ __launch_bounds__(512, 2) void lstm_step(
    const __hip_bfloat16* __restrict__ hprev,   // [1024][1024] swizzled
    const __hip_bfloat16* __restrict__ Bpk,     // packed Wh (8 MB)
    const __hip_bfloat16* __restrict__ Epr,     // [V][4096] col=4h+g
    const int* __restrict__ X,
    float* __restrict__ cbuf,                   // [1024][1024] f32
    __hip_bfloat16* __restrict__ hnext,         // swizzled
    __hip_bfloat16* __restrict__ hfin,          // swizzled (last step)
    int t, int last) {
  extern __shared__ __align__(16) char smem[];  // 98304 = 3 x 32KB A bufs
  float* gacc = (float*)smem;                   // [128][132] f32 (aliases)

  const int tid = threadIdx.x;
  const int lane = tid & 63;
  const int w = tid >> 6;
  const int wm = (w >> 1) & 1;
  const int wn = w & 1;
  const int kh = w >> 2;
  const int bid = blockIdx.x;
  const int xcd = bid & 7;
  const int j = bid >> 3;
  const int ht = xcd * 4 + (j & 3);   // Bpk slice pinned to one XCD's L2
  const int mt = j >> 2;
  const int m0 = mt * 128;
  const int h0 = ht * 32;

  const int fr = lane & 15;
  const int kb = (lane >> 4) * 16;
  const int swz = (fr & 7) << 4;
  const int cn = lane & 15;
  const int rb = (lane >> 4) * 4;

  const int crow = tid >> 2;
  const int hq = tid & 3;
  const int prow = m0 + crow;
  const int tok1 = X[prow * SEQ_ + t];

  // per-wave packed-B base (shorts)
  const __hip_bfloat16* bb =
      Bpk + (size_t)(((ht * 2 + wn) * 2 + kh) * 64) * 512 + lane * 8;

  f32x4 acc[4][4];  // [fm][gate]
#pragma unroll
  for (int i = 0; i < 4; ++i)
#pragma unroll
    for (int g = 0; g < 4; ++g) acc[i][g] = (f32x4)(0.0f);

  auto STAGE_A = [&](int kc, int b) {
#pragma unroll
    for (int q = 0; q < 4; ++q) {
      const int region = q >> 1;           // kh-half
      const int r = (q & 1) * 512 + tid;   // 0..1023 chunks
      const int row = r >> 3, ch = r & 7;
      const __hip_bfloat16* src =
          hprev + (size_t)(m0 + row) * HID_ + region * 512 + kc * 64 + ch * 8;
      async_copy16(smem + b * 32768 + region * 16384 + r * 16, src);
    }
  };

  short8 bR[2][2][4];  // [kc&1][kk][g]

  // prologue: A(0), B(0), A(1)   (order matters for vmcnt accounting)
  STAGE_A(0, 0);
#pragma unroll
  for (int kk = 0; kk < 2; ++kk)
#pragma unroll
    for (int g = 0; g < 4; ++g)
      bR[0][kk][g] = *(const short8*)(bb + (0 * 8 + kk * 4 + g) * 512);
  STAGE_A(1, 1);

#pragma unroll
  for (int kc = 0; kc < 8; ++kc) {
    __builtin_amdgcn_s_barrier();          // all waves done with buf (kc-1)%3
    if (kc + 1 < 8) {
#pragma unroll
      for (int kk = 0; kk < 2; ++kk)
#pragma unroll
        for (int g = 0; g < 4; ++g)
          bR[(kc + 1) & 1][kk][g] =
              *(const short8*)(bb + ((kc + 1) * 8 + kk * 4 + g) * 512);
    }
    if (kc + 2 < 8) STAGE_A(kc + 2, (kc + 2) % 3);
    if (kc < 6)      asm volatile("s_waitcnt vmcnt(24)" ::: "memory");
    else if (kc == 6) asm volatile("s_waitcnt vmcnt(20)" ::: "memory");
    else             asm volatile("s_waitcnt vmcnt(8)" ::: "memory");
    __builtin_amdgcn_sched_barrier(0);

    const char* baseA = smem + (kc % 3) * 32768 + kh * 16384;
    short8 aR[2][4];
#pragma unroll
    for (int kk = 0; kk < 2; ++kk)
#pragma unroll
      for (int f = 0; f < 4; ++f)
        aR[kk][f] = *(const short8*)(baseA + (wm * 64 + f * 16 + fr) * 128 +
                                     ((kk * 64 + kb) ^ swz));
    __builtin_amdgcn_s_setprio(1);
#pragma unroll
    for (int fm = 0; fm < 4; ++fm)
#pragma unroll
      for (int g = 0; g < 4; ++g) {
        mfma_acc(acc[fm][g], aR[0][fm], bR[kc & 1][0][g]);
        mfma_acc(acc[fm][g], aR[1][fm], bR[kc & 1][1][g]);
      }
    __builtin_amdgcn_s_setprio(0);
  }

  // ---- Eps gather + c load (post-loop: lower VGPR peak; hides under merge)
  ushort4 ep[8];
  float cold[8];
#pragma unroll
  for (int jj = 0; jj < 8; ++jj) {
    ep[jj] = *(const ushort4*)(Epr + (size_t)tok1 * G4_ + (h0 + hq * 8 + jj) * 4);
    cold[jj] = cbuf[(size_t)prow * HID_ + h0 + hq * 8 + jj];
  }

  // ---- merge K-half partials in LDS (gacc col = 4*h_local + gate)
  __syncthreads();
  if (kh == 0) {
#pragma unroll
    for (int fm = 0; fm < 4; ++fm)
#pragma unroll
      for (int g = 0; g < 4; ++g)
#pragma unroll
        for (int r = 0; r < 4; ++r)
          gacc[(wm * 64 + fm * 16 + rb + r) * 132 + (wn * 16 + cn) * 4 + g] =
              acc[fm][g][r];
  }
  __syncthreads();
  if (kh == 1) {
#pragma unroll
    for (int fm = 0; fm < 4; ++fm)
#pragma unroll
      for (int g = 0; g < 4; ++g)
#pragma unroll
        for (int r = 0; r < 4; ++r)
          gacc[(wm * 64 + fm * 16 + rb + r) * 132 + (wn * 16 + cn) * 4 + g] +=
              acc[fm][g][r];
  }
  __syncthreads();

  // ---- fused cell: thread = (crow, hq), 8 h each, all 4 gates local
  const float* gr = gacc + crow * 132 + hq * 32;
  f32x4 cnew0, cnew1;
  short8 hv;
#pragma unroll
  for (int jj = 0; jj < 8; ++jj) {
    const f32x4 g4 = *(const f32x4*)(gr + jj * 4);
    const float iv = sigmoidf_(g4[0] + bf2f_(ep[jj].x));
    const float fv = sigmoidf_(g4[1] + bf2f_(ep[jj].y));
    const float gv = tanhf_(g4[2] + bf2f_(ep[jj].z));
    const float ov = sigmoidf_(g4[3] + bf2f_(ep[jj].w));
    const float cv = fv * cold[jj] + iv * gv;
    if (jj < 4) cnew0[jj] = cv; else cnew1[jj - 4] = cv;
    const float hval = ov * tanhf_(cv);
    const __hip_bfloat16 hb = __float2bfloat16(hval);
    hv[jj] = *reinterpret_cast<const short*>(&hb);
  }
  float* cdst = cbuf + (size_t)prow * HID_ + h0 + hq * 8;
  *(f32x4*)cdst = cnew0;
  *(f32x4*)(cdst + 4) = cnew1;
  const int hcolb = h0 + hq * 8;
  const int hswb = (hcolb & ~63) | ((hcolb & 63) ^ ((prow & 7) << 3));
  *(short8*)(hnext + (size_t)prow * HID_ + hswb) = hv;
  if (last) *(short8*)(hfin + (size_t)prow * HID_ + hswb) = hv;
}

// fp32 -> bf16 flat convert; SWZ: k-XOR-swizzle per 64-col group (1024 cols)
template <bool SWZ>
__global__ __launch_bounds__(256) void conv_bf16_k(const float* __restrict__ in,
                                                   __hip_bfloat16* __restrict__ out, int n4) {
  const int i = blockIdx.x * 256 + threadIdx.x;
  if (i >= n4) return;
  const float4 v = ((const float4*)in)[i];
  int o = i * 4;
  if (SWZ) {
    const int row = o >> 10, col = o & 1023;
    const int cs = (col & ~63) | ((col & 63) ^ ((row & 7) << 3));
    o = (o & ~1023) | cs;
  }
  out[o + 0] = __float2bfloat16(v.x);
  out[o + 1] = __float2bfloat16(v.y);
  out[o + 2] = __float2bfloat16(v.z);
  out[o + 3] = __float2bfloat16(v.w);
}

// in[R][C] fp32 -> out[C][R] bf16; PERM: gate-interleave out-rows (4h+g);
// SWZ: XOR-swizzle k per 64-group by out-row&7.
template <bool PERM, bool SWZ>
__global__ __launch_bounds__(256) void transpose_conv(const float* __restrict__ in,
                                                      __hip_bfloat16* __restrict__ out,
                                                      int R, int C) {
  __shared__ float tile[32][33];
  const int c0 = blockIdx.x * 32, r0 = blockIdx.y * 32;
  const int tx = threadIdx.x, ty = threadIdx.y;  // 32x8
#pragma unroll
  for (int i = 0; i < 4; ++i) {
    const int r = r0 + ty + i * 8, cc = c0 + tx;
    tile[ty + i * 8][tx] = (r < R && cc < C) ? in[(size_t)r * C + cc] : 0.f;
  }
  __syncthreads();
#pragma unroll
  for (int i = 0; i < 4; ++i) {
    const int ro = c0 + ty + i * 8, co = r0 + tx;
    if (ro < C && co < R) {
      const int n = PERM ? ((ro & 1023) * 4 + (ro >> 10)) : ro;
      int k = co;
      if (SWZ) k = (k & ~63) | ((k & 63) ^ ((n & 7) << 3));
      out[(size_t)n * R + k] = __float2bfloat16(tile[tx][ty + i * 8]);
    }
  }
}

// bP[4h+g] = bx[g*1024+h] + bh[g*1024+h]
__global__ __launch_bounds__(256) void bias_perm(const float* __restrict__ bx,
                                                 const float* __restrict__ bh,
                                                 float* __restrict__ bP) {
  const int n = blockIdx.x * 256 + threadIdx.x;
  if (n >= G4_) return;
  const int h = n >> 2, g = n & 3;
  bP[n] = bx[g * HID_ + h] + bh[g * HID_ + h];
}

extern "C" void kernel_launch(void* const* d_in, const int* in_sizes, int n_in,
                              void* d_out, int out_size, void* d_ws, size_t ws_size,
                              hipStream_t stream) {
  const int* X = (const int*)d_in[0];
  const float* C = (const float*)d_in[1];
  const float* Wx = (const float*)d_in[2];
  const float* bx = (const float*)d_in[3];
  const float* Wh = (const float*)d_in[4];
  const float* bh = (const float*)d_in[5];
  const float* Wo = (const float*)d_in[6];
  const float* bo = (const float*)d_in[7];
  float* out = (float*)d_out;

  char* p = (char*)d_ws;
  const size_t szCb  = (size_t)NCLS_ * EMB_ * 2;   // Cb, reused for Wot
  const size_t szWxt = (size_t)G4_ * EMB_ * 2;
  const size_t szBpk = (size_t)G4_ * HID_ * 2;     // packed Wh
  const size_t szEpr = (size_t)NCLS_ * G4_ * 2;
  const size_t szH   = (size_t)BATCH_ * HID_ * 2;  // x3: hA, hB, hfin
  const size_t szC   = (size_t)BATCH_ * HID_ * 4;
  const size_t szBp  = (size_t)G4_ * 4;
  if (ws_size < szCb + szWxt + szBpk + szEpr + 3 * szH + szC + szBp) return;

  __hip_bfloat16* Cb   = (__hip_bfloat16*)p; p += szCb;
  __hip_bfloat16* WxtP = (__hip_bfloat16*)p; p += szWxt;
  __hip_bfloat16* Bpk  = (__hip_bfloat16*)p; p += szBpk;
  __hip_bfloat16* Epr  = (__hip_bfloat16*)p; p += szEpr;
  __hip_bfloat16* hA   = (__hip_bfloat16*)p; p += szH;
  __hip_bfloat16* hB   = (__hip_bfloat16*)p; p += szH;
  __hip_bfloat16* hfin = (__hip_bfloat16*)p; p += szH;
  float* cbuf          = (float*)p;          p += szC;
  float* bP            = (float*)p;          p += szBp;

  // 1. C -> bf16, k-swizzled (A operand of E_proj GEMM)
  {
    const int n4 = NCLS_ * EMB_ / 4;
    conv_bf16_k<true><<<(n4 + 255) / 256, 256, 0, stream>>>(C, Cb, n4);
  }
  // 2. Wx -> [4096][1024] gate-interleaved rows, k-swizzled
  transpose_conv<true, true><<<dim3(G4_ / 32, EMB_ / 32), dim3(32, 8), 0, stream>>>(
      Wx, WxtP, EMB_, G4_);
  // 3. Wh -> fragment-packed Bpk (direct-to-register B operand)
  pack_b<<<2048, 256, 0, stream>>>(Wh, Bpk);
  // 4. permuted bias
  bias_perm<<<G4_ / 256, 256, 0, stream>>>(bx, bh, bP);

  // 5. Epr[V][4096] = C @ Wx (gate-interleaved cols) + (bx+bh)
  gemm_bt<0><<<dim3(G4_ / 128, (NCLS_ + 127) / 128), 256, 0, stream>>>(
      Cb, WxtP, nullptr, Epr, NCLS_, G4_, EMB_, G4_, bP);

  // 6. zero initial state (zeros are swizzle-invariant)
  hipMemsetAsync(hA, 0, szH, stream);
  hipMemsetAsync(cbuf, 0, szC, stream);

  // 7. 128 fused LSTM steps (ping-pong h buffers), 96 KB dynamic LDS
  for (int t = 0; t < SEQ_; ++t) {
    const __hip_bfloat16* hp = (t & 1) ? hB : hA;
    __hip_bfloat16* hn = (t & 1) ? hA : hB;
    lstm_step<<<256, 512, 98304, stream>>>(hp, Bpk, Epr, X, cbuf, hn, hfin, t,
                                           (int)(t == SEQ_ - 1));
  }

  // 8. W_out^T, k-swizzled, into Cb region (dead after step 5)
  __hip_bfloat16* Wot = Cb;
  transpose_conv<false, true><<<dim3((NCLS_ + 31) / 32, HID_ / 32), dim3(32, 8), 0,
                                stream>>>(Wo, Wot, HID_, NCLS_);

  // 9. logits = hfin @ W_out + b_out
  gemm_bt<2><<<dim3((NCLS_ + 127) / 128, BATCH_ / 128), 256, 0, stream>>>(
      hfin, Wot, out, nullptr, BATCH_, NCLS_, HID_, NCLS_, bo);
}